// Round 1
// baseline (392.380 us; speedup 1.0000x reference)
//
#include <hip/hip_runtime.h>
#include <math.h>

// Fused ConvTranspose2d(64->64,k4,s2,p1) + BN(inference) + softmax(C) + maxpool2x2
// x: [32,64,64,64] f32, weight: [cin=64][cout=64][4][4], out: [32,64,64,64] f32
//
// Mapping: block = (n, ph) pooled row. 256 threads = 4 waves.
// wave w: r = w>>1 (pre-pool row parity), p = w&1 (col parity); lane l -> ow = 2l+p.
// Each thread computes ALL 64 cout for its pre-pool position (stride-2 parity =>
// exactly 4 (kh,kw) taps, wave-uniform), does softmax thread-locally, then the
// 4 waves max-reduce (2x2 pool) through LDS.

__device__ float g_wt[64 * 64 * 16];  // [kh*4+kw][cin][cout]  (cout contiguous)
__device__ float g_aff[128];          // A[64] = gamma*rsqrt(var+eps); D[64] = (bias-mean)*A+beta

__global__ __launch_bounds__(256) void prep_kernel(
    const float* __restrict__ w, const float* __restrict__ bias,
    const float* __restrict__ gamma, const float* __restrict__ beta,
    const float* __restrict__ mean, const float* __restrict__ var) {
  int tid = threadIdx.x;
  for (int e = tid; e < 64 * 64 * 16; e += 256) {
    int cout = e & 63;
    int cin  = (e >> 6) & 63;
    int khkw = e >> 12;
    g_wt[e] = w[(cin * 64 + cout) * 16 + khkw];
  }
  if (tid < 64) {
    float A = gamma[tid] * rsqrtf(var[tid] + 1e-5f);
    g_aff[tid] = A;
    g_aff[64 + tid] = (bias[tid] - mean[tid]) * A + beta[tid];
  }
}

__global__ __launch_bounds__(256) void fused_kernel(const float* __restrict__ x,
                                                    float* __restrict__ out) {
  // x rows staged per cin-half: [3 rows][32 cin][66 cols] (col 0 and 65 are zero pads)
  __shared__ float xs[3 * 32 * 66];
  __shared__ float red[4][64][17];  // +1 pad breaks 16-float-stride bank conflicts

  const int tid  = threadIdx.x;
  const int ph   = blockIdx.x;  // pooled row 0..63
  const int n    = blockIdx.y;  // batch 0..31
  const int wave = tid >> 6;
  const int lane = tid & 63;
  const int r = wave >> 1;  // pre-pool row within the pair (oh = 2*ph + r)
  const int p = wave & 1;   // column parity (ow = 2*lane + p)

  // Valid taps for stride=2, pad=1, k=4: ih=(oh+1-kh)/2 integer.
  // oh even (r=0): kh=1 -> ih=ph (LDS row 1); kh=3 -> ih=ph-1 (row 0)
  // oh odd  (r=1): kh=0 -> ih=ph+1 (row 2);   kh=2 -> ih=ph   (row 1)
  // ow even (p=0): kw=1 -> iw=l (dx=0); kw=3 -> iw=l-1 (dx=-1)
  // ow odd  (p=1): kw=0 -> iw=l+1 (dx=+1); kw=2 -> iw=l (dx=0)
  const int khA = r ? 0 : 1, rowA = r ? 2 : 1;
  const int khB = r ? 2 : 3, rowB = r ? 1 : 0;
  const int kwA = p ? 0 : 1, dxA = p ? 1 : 0;
  const int kwB = p ? 2 : 3, dxB = p ? 0 : -1;

  float acc[64];
#pragma unroll
  for (int i = 0; i < 64; ++i) acc[i] = 0.f;

  for (int half = 0; half < 2; ++half) {
    __syncthreads();  // protect xs reuse across halves
    // stage 3 x-rows (ph-1, ph, ph+1) for 32 cin, zero-padded cols & OOB rows
    for (int e = tid; e < 3 * 32 * 66; e += 256) {
      int col = e % 66;
      int t2  = e / 66;
      int cin = t2 & 31;
      int row = t2 >> 5;
      int ih = ph - 1 + row;
      int iw = col - 1;
      float v = 0.f;
      if (ih >= 0 && ih < 64 && iw >= 0 && iw < 64)
        v = x[((n * 64 + half * 32 + cin) * 64 + ih) * 64 + iw];
      xs[e] = v;
    }
    __syncthreads();

#pragma unroll
    for (int t = 0; t < 4; ++t) {
      const int kh  = (t < 2) ? khA : khB;
      const int row = (t < 2) ? rowA : rowB;
      const int kw  = (t & 1) ? kwB : kwA;
      const int dx  = (t & 1) ? dxB : dxA;
      int wofs = ((kh * 4 + kw) * 64 + half * 32) * 64;
      wofs = __builtin_amdgcn_readfirstlane(wofs);  // wave-uniform -> scalar loads
      const float* wp = g_wt + wofs;
      const float* xp = xs + row * 32 * 66 + (lane + dx + 1);
      for (int ci = 0; ci < 32; ++ci) {
        float xv = xp[ci * 66];  // per-lane stride-1 LDS read, conflict-free
        const float4* w4 = (const float4*)(wp + ci * 64);
#pragma unroll
        for (int j = 0; j < 16; ++j) {
          float4 wv = w4[j];
          acc[4 * j + 0] = fmaf(xv, wv.x, acc[4 * j + 0]);
          acc[4 * j + 1] = fmaf(xv, wv.y, acc[4 * j + 1]);
          acc[4 * j + 2] = fmaf(xv, wv.z, acc[4 * j + 2]);
          acc[4 * j + 3] = fmaf(xv, wv.w, acc[4 * j + 3]);
        }
      }
    }
  }

  // fold BN affine, softmax over channels (all in-thread)
  float m = -1e30f;
#pragma unroll
  for (int c = 0; c < 64; ++c) {
    float yv = fmaf(acc[c], g_aff[c], g_aff[64 + c]);
    acc[c] = yv;
    m = fmaxf(m, yv);
  }
  float s = 0.f;
#pragma unroll
  for (int c = 0; c < 64; ++c) {
    float e = __expf(acc[c] - m);
    acc[c] = e;
    s += e;
  }
  float inv = 1.0f / s;
#pragma unroll
  for (int c = 0; c < 64; ++c) acc[c] *= inv;

  // 2x2 maxpool: the 4 positions of pooled (ph, pw=lane) live in the 4 waves at
  // the same lane. Reduce via LDS in 16-channel chunks.
#pragma unroll
  for (int c0 = 0; c0 < 64; c0 += 16) {
    __syncthreads();
#pragma unroll
    for (int j = 0; j < 16; ++j) red[wave][lane][j] = acc[c0 + j];
    __syncthreads();
    if (wave == 0) {
#pragma unroll
      for (int j = 0; j < 16; ++j) {
        float v0 = red[0][lane][j], v1 = red[1][lane][j];
        float v2 = red[2][lane][j], v3 = red[3][lane][j];
        float mx = fmaxf(fmaxf(v0, v1), fmaxf(v2, v3));
        out[((n * 64 + c0 + j) * 64 + ph) * 64 + lane] = mx;
      }
    }
  }
}

extern "C" void kernel_launch(void* const* d_in, const int* in_sizes, int n_in,
                              void* d_out, int out_size, void* d_ws, size_t ws_size,
                              hipStream_t stream) {
  const float* x     = (const float*)d_in[0];
  const float* w     = (const float*)d_in[1];
  const float* bias  = (const float*)d_in[2];
  const float* gamma = (const float*)d_in[3];
  const float* beta  = (const float*)d_in[4];
  const float* mean  = (const float*)d_in[5];
  const float* var   = (const float*)d_in[6];
  float* out = (float*)d_out;

  prep_kernel<<<1, 256, 0, stream>>>(w, bias, gamma, beta, mean, var);
  dim3 grid(64, 32);  // (ph, n)
  fused_kernel<<<grid, 256, 0, stream>>>(x, out);
}

// Round 2
// 313.840 us; speedup vs baseline: 1.2503x; 1.2503x over previous
//
#include <hip/hip_runtime.h>
#include <math.h>

// Fused ConvTranspose2d(64->64,k4,s2,p1) + BN(inference) + softmax(C) + maxpool2x2
// x: [32,64,64,64] f32, weight: [cin=64][cout=64][4][4], out: [32,64,64,64] f32
//
// Mapping: block = (n, ph) pooled row. 256 threads = 4 waves.
// wave w: r = w>>1 (pre-pool row parity), p = w&1 (col parity); lane l -> ow = 2l+p.
// Each thread computes ALL 64 cout for its pre-pool position (stride-2 parity =>
// exactly 4 (kh,kw) taps, wave-uniform), does softmax thread-locally, then the
// 4 waves max-reduce (2x2 pool) through LDS.
//
// R2: (a) pooling buffer overlaid on xs -> LDS 43008->25344 B (3->6 blocks/CU),
//     (b) prep kernel parallelized 1->64 blocks, (c) ci-loop unrolled x4,
//     (d) pooled stores spread over all 4 waves.

__device__ float g_wt[64 * 64 * 16];  // [kh*4+kw][cin][cout]  (cout contiguous)
__device__ float g_aff[128];          // A = gamma*rsqrt(var+eps); D = (bias-mean)*A+beta

__global__ __launch_bounds__(256) void prep_kernel(
    const float* __restrict__ w, const float* __restrict__ bias,
    const float* __restrict__ gamma, const float* __restrict__ beta,
    const float* __restrict__ mean, const float* __restrict__ var) {
  int tid = blockIdx.x * 256 + threadIdx.x;
  for (int e = tid; e < 64 * 64 * 16; e += 64 * 256) {
    int cout = e & 63;
    int cin  = (e >> 6) & 63;
    int khkw = e >> 12;
    g_wt[e] = w[(cin * 64 + cout) * 16 + khkw];
  }
  if (blockIdx.x == 0 && threadIdx.x < 64) {
    int c = threadIdx.x;
    float A = gamma[c] * rsqrtf(var[c] + 1e-5f);
    g_aff[c] = A;
    g_aff[64 + c] = (bias[c] - mean[c]) * A + beta[c];
  }
}

__global__ __launch_bounds__(256) void fused_kernel(const float* __restrict__ x,
                                                    float* __restrict__ out) {
  // smem dual-use: compute phase = x rows [3][32 cin][66 cols] (6336 floats);
  // pooling phase = red[4][64][17] (4352 floats).
  __shared__ float smem[3 * 32 * 66];

  const int tid  = threadIdx.x;
  const int ph   = blockIdx.x;  // pooled row 0..63
  const int n    = blockIdx.y;  // batch 0..31
  const int wave = tid >> 6;
  const int lane = tid & 63;
  const int r = wave >> 1;  // pre-pool row within the pair (oh = 2*ph + r)
  const int p = wave & 1;   // column parity (ow = 2*lane + p)

  // Valid taps for stride=2, pad=1, k=4: ih=(oh+1-kh)/2 must be integral.
  // oh even (r=0): kh=1 -> ih=ph (LDS row 1); kh=3 -> ih=ph-1 (row 0)
  // oh odd  (r=1): kh=0 -> ih=ph+1 (row 2);   kh=2 -> ih=ph   (row 1)
  // ow even (p=0): kw=1 -> iw=l (dx=0); kw=3 -> iw=l-1 (dx=-1)
  // ow odd  (p=1): kw=0 -> iw=l+1 (dx=+1); kw=2 -> iw=l (dx=0)
  const int khA = r ? 0 : 1, rowA = r ? 2 : 1;
  const int khB = r ? 2 : 3, rowB = r ? 1 : 0;
  const int kwA = p ? 0 : 1, dxA = p ? 1 : 0;
  const int kwB = p ? 2 : 3, dxB = p ? 0 : -1;

  float acc[64];
#pragma unroll
  for (int i = 0; i < 64; ++i) acc[i] = 0.f;

  for (int half = 0; half < 2; ++half) {
    __syncthreads();  // protect smem reuse across halves
    // stage 3 x-rows (ph-1, ph, ph+1) for 32 cin, zero-padded cols & OOB rows
    for (int e = tid; e < 3 * 32 * 66; e += 256) {
      int col = e % 66;
      int t2  = e / 66;
      int cin = t2 & 31;
      int row = t2 >> 5;
      int ih = ph - 1 + row;
      int iw = col - 1;
      float v = 0.f;
      if (ih >= 0 && ih < 64 && iw >= 0 && iw < 64)
        v = x[((n * 64 + half * 32 + cin) * 64 + ih) * 64 + iw];
      smem[e] = v;
    }
    __syncthreads();

#pragma unroll
    for (int t = 0; t < 4; ++t) {
      const int kh  = (t < 2) ? khA : khB;
      const int row = (t < 2) ? rowA : rowB;
      const int dx  = (t & 1) ? dxB : dxA;
      const int kw  = (t & 1) ? kwB : kwA;
      int wofs = ((kh * 4 + kw) * 64 + half * 32) * 64;
      wofs = __builtin_amdgcn_readfirstlane(wofs);  // wave-uniform -> scalar loads
      const float* wp = g_wt + wofs;
      const float* xp = smem + row * 32 * 66 + (lane + dx + 1);
      for (int ci = 0; ci < 32; ci += 4) {
        // 4 outstanding LDS reads (per-lane stride-1, conflict-free)
        float xv0 = xp[(ci + 0) * 66];
        float xv1 = xp[(ci + 1) * 66];
        float xv2 = xp[(ci + 2) * 66];
        float xv3 = xp[(ci + 3) * 66];
#pragma unroll
        for (int k = 0; k < 4; ++k) {
          float xv = (k == 0) ? xv0 : (k == 1) ? xv1 : (k == 2) ? xv2 : xv3;
          const float4* w4 = (const float4*)(wp + (ci + k) * 64);
#pragma unroll
          for (int j = 0; j < 16; ++j) {
            float4 wv = w4[j];
            acc[4 * j + 0] = fmaf(xv, wv.x, acc[4 * j + 0]);
            acc[4 * j + 1] = fmaf(xv, wv.y, acc[4 * j + 1]);
            acc[4 * j + 2] = fmaf(xv, wv.z, acc[4 * j + 2]);
            acc[4 * j + 3] = fmaf(xv, wv.w, acc[4 * j + 3]);
          }
        }
      }
    }
  }

  // fold BN affine, softmax over channels (all in-thread)
  float m = -1e30f;
#pragma unroll
  for (int c = 0; c < 64; ++c) {
    float yv = fmaf(acc[c], g_aff[c], g_aff[64 + c]);
    acc[c] = yv;
    m = fmaxf(m, yv);
  }
  float s = 0.f;
#pragma unroll
  for (int c = 0; c < 64; ++c) {
    float e = __expf(acc[c] - m);
    acc[c] = e;
    s += e;
  }
  float inv = 1.0f / s;
#pragma unroll
  for (int c = 0; c < 64; ++c) acc[c] *= inv;

  // 2x2 maxpool: the 4 positions of pooled (ph, pw=lane) live in the 4 waves at
  // the same lane. Reduce via LDS (overlaid on smem) in 16-channel chunks.
  float (*red)[64][17] = (float (*)[64][17])smem;  // [wave][lane][chan] +1 pad
#pragma unroll
  for (int c0 = 0; c0 < 64; c0 += 16) {
    __syncthreads();  // smem free (compute done / previous chunk read)
#pragma unroll
    for (int j = 0; j < 16; ++j) red[wave][lane][j] = acc[c0 + j];
    __syncthreads();
    // each wave stores 4 of the 16 channels -> all waves busy, coalesced stores
#pragma unroll
    for (int jj = 0; jj < 4; ++jj) {
      int j = wave * 4 + jj;
      float v0 = red[0][lane][j], v1 = red[1][lane][j];
      float v2 = red[2][lane][j], v3 = red[3][lane][j];
      float mx = fmaxf(fmaxf(v0, v1), fmaxf(v2, v3));
      out[((n * 64 + c0 + j) * 64 + ph) * 64 + lane] = mx;
    }
  }
}

extern "C" void kernel_launch(void* const* d_in, const int* in_sizes, int n_in,
                              void* d_out, int out_size, void* d_ws, size_t ws_size,
                              hipStream_t stream) {
  const float* x     = (const float*)d_in[0];
  const float* w     = (const float*)d_in[1];
  const float* bias  = (const float*)d_in[2];
  const float* gamma = (const float*)d_in[3];
  const float* beta  = (const float*)d_in[4];
  const float* mean  = (const float*)d_in[5];
  const float* var   = (const float*)d_in[6];
  float* out = (float*)d_out;

  prep_kernel<<<64, 256, 0, stream>>>(w, bias, gamma, beta, mean, var);
  dim3 grid(64, 32);  // (ph, n)
  fused_kernel<<<grid, 256, 0, stream>>>(x, out);
}

// Round 3
// 139.269 us; speedup vs baseline: 2.8174x; 2.2535x over previous
//
#include <hip/hip_runtime.h>
#include <math.h>

// Fused ConvTranspose2d(64->64,k4,s2,p1) + BN + softmax(C) + maxpool2x2 via bf16 MFMA.
//
// Parity decomposition: output (oh,ow) = (2ph+r, 2pw+p). Each class (r,p) is a GEMM
//   Y[m=(n,ph,pw)][cout] = sum_{tap,cin} Xhalo * W'   (K = 4 taps x 64 cin = 256)
// All 4 classes share the same m index -> maxpool = register max across classes.
// Block = (ph, n): 64 pw positions, 4 waves x 16 rows. MFMA 16x16x32 bf16,
// N = 64 couts = 4 N-tiles, K = 256 = 8 k-steps.
//
// LDS x tile: [3 rows][66 cols][cin 64, pitch 72 ushort] bf16 (pitch 72 = 144B:
// 16B-aligned b128 frags; sequential 8-lane phases hit distinct bank groups).
// Weights pre-arranged in exact B-frag order: g_wfrag[class][ks][nt][lane][j].

typedef __attribute__((ext_vector_type(8))) short short8;
typedef __attribute__((ext_vector_type(4))) float floatx4;

#define PITCH 72
#define COLS 66

__device__ ushort g_wfrag[4 * 8 * 4 * 64 * 8];  // 128 KB, B-fragment order
__device__ float g_aff[128];  // A = gamma*rsqrt(var+eps); D = (bias-mean)*A+beta

__device__ __forceinline__ ushort f2bf(float f) {
  union { float f; unsigned u; } v; v.f = f;
  unsigned r = v.u + 0x7FFF + ((v.u >> 16) & 1);  // RNE
  return (ushort)(r >> 16);
}

__global__ __launch_bounds__(256) void prep_kernel(
    const float* __restrict__ w, const float* __restrict__ bias,
    const float* __restrict__ gamma, const float* __restrict__ beta,
    const float* __restrict__ mean, const float* __restrict__ var) {
  int tid = blockIdx.x * 256 + threadIdx.x;
  // layout bits: [c:2][ks:3][nt:2][lane:6][j:3]
  for (int e = tid; e < 4 * 8 * 4 * 64 * 8; e += 64 * 256) {
    int j    = e & 7;
    int lane = (e >> 3) & 63;
    int nt   = (e >> 9) & 3;
    int ks   = (e >> 11) & 7;
    int c    = (e >> 14) & 3;
    int k    = ks * 32 + (lane >> 4) * 8 + j;  // B-frag: k = quad*8+j within k-step
    int tap  = k >> 6, cin = k & 63;
    int cout = nt * 16 + (lane & 15);
    int r = c >> 1, p = c & 1;
    int a = tap >> 1, b = tap & 1;
    int kh = r ? (a ? 2 : 0) : (a ? 3 : 1);
    int kw = p ? (b ? 2 : 0) : (b ? 3 : 1);
    g_wfrag[e] = f2bf(w[(cin * 64 + cout) * 16 + kh * 4 + kw]);
  }
  if (blockIdx.x == 0 && threadIdx.x < 64) {
    int c = threadIdx.x;
    float A = gamma[c] * rsqrtf(var[c] + 1e-5f);
    g_aff[c] = A;
    g_aff[64 + c] = (bias[c] - mean[c]) * A + beta[c];
  }
}

__global__ __launch_bounds__(256) void fused_kernel(const float* __restrict__ x,
                                                    float* __restrict__ out) {
  __shared__ ushort xs[3 * COLS * PITCH];  // 30096 B; reused as f32 red[64][66] later

  const int tid  = threadIdx.x;
  const int ph   = blockIdx.x;  // pooled row
  const int n    = blockIdx.y;  // batch
  const int wave = tid >> 6;
  const int lane = tid & 63;
  const int b15  = lane & 15;   // A row m / B col n within tile
  const int q    = lane >> 4;   // quad

  // ---- stage x halo: rows ph-1..ph+1, all 64 cin, bf16, [row][col][cin] ----
  // thread packs 4 cins (one ds_write_b64); global loads stay iw-coalesced.
  for (int e = tid; e < 3 * 16 * 64; e += 256) {
    int iw  = e & 63;
    int c4  = (e >> 6) & 15;
    int row = e >> 10;
    int ih  = ph - 1 + row;
    int cin = c4 * 4;
    float v0 = 0.f, v1 = 0.f, v2 = 0.f, v3 = 0.f;
    if (ih >= 0 && ih < 64) {
      const float* xp = x + ((n * 64 + cin) * 64 + ih) * 64 + iw;
      v0 = xp[0]; v1 = xp[4096]; v2 = xp[8192]; v3 = xp[12288];
    }
    ushort4 pk;
    pk.x = f2bf(v0); pk.y = f2bf(v1); pk.z = f2bf(v2); pk.w = f2bf(v3);
    *(ushort4*)&xs[(row * COLS + iw + 1) * PITCH + cin] = pk;
  }
  // zero-pad cols 0 and 65
  for (int e = tid; e < 3 * 2 * 16; e += 256) {
    int c4  = e & 15;
    int side = (e >> 4) & 1;
    int row = e >> 5;
    ushort4 z; z.x = z.y = z.z = z.w = 0;
    *(ushort4*)&xs[(row * COLS + (side ? 65 : 0)) * PITCH + c4 * 4] = z;
  }
  __syncthreads();

  // per-lane BN coefficients for couts {nt*16 + b15}
  float Ac[4], Dc[4];
#pragma unroll
  for (int nt = 0; nt < 4; ++nt) {
    Ac[nt] = g_aff[nt * 16 + b15];
    Dc[nt] = g_aff[64 + nt * 16 + b15];
  }

  float pooled[16];
#pragma unroll
  for (int i = 0; i < 16; ++i) pooled[i] = 0.f;  // softmax outputs > 0

#pragma unroll
  for (int c = 0; c < 4; ++c) {
    const int r = c >> 1, p = c & 1;
    floatx4 acc[4];
#pragma unroll
    for (int nt = 0; nt < 4; ++nt) acc[nt] = (floatx4){0.f, 0.f, 0.f, 0.f};

#pragma unroll
    for (int ks = 0; ks < 8; ++ks) {
      const int tap = ks >> 1, a = tap >> 1, b = tap & 1;
      const int row = r ? (a ? 1 : 2) : (a ? 0 : 1);   // LDS halo row
      const int dx  = p ? (b ? 0 : 1) : (b ? -1 : 0);  // col offset
      const int col = wave * 16 + b15 + dx + 1;
      const int cin0 = (ks & 1) * 32 + q * 8;
      short8 afrag = *(const short8*)&xs[(row * COLS + col) * PITCH + cin0];
      const short8* wf = (const short8*)&g_wfrag[((c * 8 + ks) * 4 * 64 + lane) * 8];
#pragma unroll
      for (int nt = 0; nt < 4; ++nt) {
        short8 bfrag = wf[nt * 64];  // [nt] stride = 64 lanes * 8
        acc[nt] = __builtin_amdgcn_mfma_f32_16x16x32_bf16(afrag, bfrag, acc[nt], 0, 0, 0);
      }
    }

    // BN affine + softmax over 64 couts (cols: lane&15 x 4 nt; rows: q*4+reg)
    float v[16], mx[4], sm[4];
#pragma unroll
    for (int reg = 0; reg < 4; ++reg) mx[reg] = -1e30f;
#pragma unroll
    for (int nt = 0; nt < 4; ++nt)
#pragma unroll
      for (int reg = 0; reg < 4; ++reg) {
        float y = fmaf(acc[nt][reg], Ac[nt], Dc[nt]);
        v[nt * 4 + reg] = y;
        mx[reg] = fmaxf(mx[reg], y);
      }
#pragma unroll
    for (int reg = 0; reg < 4; ++reg) {
      mx[reg] = fmaxf(mx[reg], __shfl_xor(mx[reg], 1, 64));
      mx[reg] = fmaxf(mx[reg], __shfl_xor(mx[reg], 2, 64));
      mx[reg] = fmaxf(mx[reg], __shfl_xor(mx[reg], 4, 64));
      mx[reg] = fmaxf(mx[reg], __shfl_xor(mx[reg], 8, 64));
      sm[reg] = 0.f;
    }
#pragma unroll
    for (int nt = 0; nt < 4; ++nt)
#pragma unroll
      for (int reg = 0; reg < 4; ++reg) {
        float e = __expf(v[nt * 4 + reg] - mx[reg]);
        v[nt * 4 + reg] = e;
        sm[reg] += e;
      }
#pragma unroll
    for (int reg = 0; reg < 4; ++reg) {
      sm[reg] += __shfl_xor(sm[reg], 1, 64);
      sm[reg] += __shfl_xor(sm[reg], 2, 64);
      sm[reg] += __shfl_xor(sm[reg], 4, 64);
      sm[reg] += __shfl_xor(sm[reg], 8, 64);
      sm[reg] = 1.0f / sm[reg];
    }
#pragma unroll
    for (int nt = 0; nt < 4; ++nt)
#pragma unroll
      for (int reg = 0; reg < 4; ++reg)
        pooled[nt * 4 + reg] =
            fmaxf(pooled[nt * 4 + reg], v[nt * 4 + reg] * sm[reg]);
  }

  // ---- transpose pooled through LDS, coalesced store ----
  __syncthreads();  // xs reads done in all waves
  float* red = (float*)xs;  // [64 cout][pitch 66]
#pragma unroll
  for (int nt = 0; nt < 4; ++nt)
#pragma unroll
    for (int reg = 0; reg < 4; ++reg) {
      int cout = nt * 16 + b15;
      int pw   = wave * 16 + q * 4 + reg;  // D row = quad*4+reg
      red[cout * 66 + pw] = pooled[nt * 4 + reg];
    }
  __syncthreads();
  for (int e = tid; e < 2048; e += 256) {
    int pwh  = e & 31;
    int cout = e >> 5;
    float2 val = *(float2*)&red[cout * 66 + pwh * 2];
    *(float2*)&out[((n * 64 + cout) * 64 + ph) * 64 + pwh * 2] = val;
  }
}

extern "C" void kernel_launch(void* const* d_in, const int* in_sizes, int n_in,
                              void* d_out, int out_size, void* d_ws, size_t ws_size,
                              hipStream_t stream) {
  const float* x     = (const float*)d_in[0];
  const float* w     = (const float*)d_in[1];
  const float* bias  = (const float*)d_in[2];
  const float* gamma = (const float*)d_in[3];
  const float* beta  = (const float*)d_in[4];
  const float* mean  = (const float*)d_in[5];
  const float* var   = (const float*)d_in[6];
  float* out = (float*)d_out;

  prep_kernel<<<64, 256, 0, stream>>>(w, bias, gamma, beta, mean, var);
  dim3 grid(64, 32);  // (ph, n)
  fused_kernel<<<grid, 256, 0, stream>>>(x, out);
}